// Round 2
// baseline (6702.177 us; speedup 1.0000x reference)
//
#include <hip/hip_runtime.h>
#include <cstdint>
#include <cstddef>

// SimpleRNN on MI355X — round 4: self-validating tagged-word handoff (hardened).
//   h1_t = tanh(x_t Wih0^T + h2_{t-1} Whh0^T + bc0)      (L0 WGs)
//   h2_t = tanh(h1_t (Wih1+Whh1)^T + b1c)                 (L1 WGs)
//   y_t  = h2_t Wout^T + bout                             (L0 WGs, off critical path)
// Handoff protocol: each h value travels as one u32 = (f16 bits << 16) | epoch.
// Consumer polls its own 16 coalesced words until all carry the expected epoch —
// the poll IS the data load. No flags, no vmcnt drain before publish, no ring
// (exact-epoch match + dataflow ordering make a single buffer per direction safe),
// one barrier per iteration (LDS stage -> MFMA). All traffic relaxed agent-scope.
// Hardening vs round 3: polls share a generous spin budget; on exhaustion they
// fall through (wrong results, but the kernel TERMINATES and returns counters
// instead of hanging the container).

typedef _Float16 f16;
typedef _Float16 f16x8 __attribute__((ext_vector_type(8)));
typedef float    f32x4 __attribute__((ext_vector_type(4)));

#define NB 128
#define NT 1024
#define NI 256
#define NH 512
#define NO 256

#define WS_WHH0 (size_t)(0)        // 512*512 f16
#define WS_W1C  (size_t)(524288)   // 512*512 f16 (Wih1+Whh1)
#define WS_WOUT (size_t)(1048576)  // 256*512 f16
#define WS_WIH0 (size_t)(1310720)  // 512*256 f16
#define WS_BC0  (size_t)(1572864)  // 512 f32
#define WS_B1C  (size_t)(1574912)  // 512 f32
#define WS_BOUT (size_t)(1576960)  // 256 f32
#define WS_H1P  (size_t)(2097152)  // [8][16][512] u32 tagged h1 panel (256 KB)
#define WS_H2P  (size_t)(2621440)  // [8][16][512] u32 tagged h2 panel (256 KB)

#define AGENT __HIP_MEMORY_SCOPE_AGENT
#define SPIN_BUDGET (1 << 24)

__device__ __forceinline__ f32x4 mfma16(f16x8 a, f16x8 b, f32x4 c) {
  return __builtin_amdgcn_mfma_f32_16x16x32_f16(a, b, c, 0, 0, 0);
}

__device__ __forceinline__ float fast_tanh(float v) {
  float a = __builtin_fabsf(v);
  float e = __expf(-2.0f * a);                       // v_exp_f32
  float r = (1.0f - e) * __builtin_amdgcn_rcpf(1.0f + e);
  return v < 0.0f ? -r : r;
}

__device__ __forceinline__ uint32_t pack_h(float v, uint32_t tag) {
  union { f16 h; uint16_t u; } cv;
  cv.h = (f16)v;
  return ((uint32_t)cv.u << 16) | tag;
}

// Poll 16 per-thread words until all carry `expect` in the low 16 bits.
// w[] holds the most recent loads on exit. Bounded by *budget (never hit in
// correct operation; guarantees termination if the protocol is broken).
__device__ __forceinline__ void poll16(uint32_t* __restrict__ panel, int tid,
                                       uint32_t expect, uint32_t w[16],
                                       int* budget) {
  for (;;) {
    bool ok = true;
    #pragma unroll
    for (int i = 0; i < 16; i++) ok &= ((w[i] & 0xFFFFu) == expect);
    if (ok) return;
    if (--(*budget) < 0) return;   // hardening: terminate, don't hang
    __builtin_amdgcn_s_sleep(1);
    #pragma unroll
    for (int i = 0; i < 16; i++)
      w[i] = __hip_atomic_load(panel + tid + i * 512, __ATOMIC_RELAXED, AGENT);
  }
}

__global__ __launch_bounds__(256) void rnn9277_prep(
    const float* __restrict__ h0,
    const float* __restrict__ Wih0, const float* __restrict__ bih0,
    const float* __restrict__ Whh0, const float* __restrict__ bhh0,
    const float* __restrict__ Wih1, const float* __restrict__ bih1,
    const float* __restrict__ Whh1, const float* __restrict__ bhh1,
    const float* __restrict__ Woutp, const float* __restrict__ boutp,
    char* __restrict__ ws)
{
  const int tid = blockIdx.x * 256 + threadIdx.x;
  const int stride = gridDim.x * 256;
  f16* whh0 = (f16*)(ws + WS_WHH0);
  f16* w1c  = (f16*)(ws + WS_W1C);
  f16* wout = (f16*)(ws + WS_WOUT);
  f16* wih0 = (f16*)(ws + WS_WIH0);
  float* bc0 = (float*)(ws + WS_BC0);
  float* b1c = (float*)(ws + WS_B1C);
  float* bo  = (float*)(ws + WS_BOUT);
  uint32_t* h1p = (uint32_t*)(ws + WS_H1P);
  uint32_t* h2p = (uint32_t*)(ws + WS_H2P);

  for (int i = tid; i < NH * NH; i += stride) whh0[i] = (f16)Whh0[i];
  for (int i = tid; i < NH * NH; i += stride) w1c[i]  = (f16)(Wih1[i] + Whh1[i]);
  for (int i = tid; i < NO * NH; i += stride) wout[i] = (f16)Woutp[i];
  for (int i = tid; i < NH * NI; i += stride) wih0[i] = (f16)Wih0[i];
  for (int i = tid; i < NH; i += stride) { bc0[i] = bih0[i] + bhh0[i]; b1c[i] = bih1[i] + bhh1[i]; }
  for (int i = tid; i < NO; i += stride) bo[i] = boutp[i];

  // h1 panel: clear to tag 0 (valid h1 tags are 1..NT) — mandatory each launch
  // so stale tags from a previous run can never alias.
  for (int i = tid; i < 8 * 8192; i += stride)
    __hip_atomic_store(h1p + i, 0u, __ATOMIC_RELAXED, AGENT);
  // h0 -> h2 panel with tag 0 (L0 at t=0 expects tag 0).
  for (int i = tid; i < NB * NH; i += stride) {
    int b = i >> 9, c = i & 511;
    int g = b >> 4, r = b & 15;
    union { f16 h; uint16_t u; } cv;
    cv.h = (f16)h0[i];
    __hip_atomic_store(h2p + (size_t)g * 8192 + r * 512 + c,
                       (uint32_t)cv.u << 16, __ATOMIC_RELAXED, AGENT);
  }
}

__global__ __launch_bounds__(512) void rnn9277_chain(
    const float* __restrict__ x, float* __restrict__ out, char* __restrict__ ws)
{
  const int wg = blockIdx.x;                 // 0..63
  const bool isL0 = wg < 32;
  const int g = (wg & 31) >> 2, j = wg & 3;  // group, column-WG
  const int tid = threadIdx.x;               // 0..511
  const int wave = tid >> 6, lane = tid & 63;
  const int row16 = lane & 15, kq = lane >> 4;

  const f16* whh0 = (const f16*)(ws + WS_WHH0);
  const f16* w1c  = (const f16*)(ws + WS_W1C);
  const f16* wout = (const f16*)(ws + WS_WOUT);
  const f16* wih0 = (const f16*)(ws + WS_WIH0);
  const float* bc0 = (const float*)(ws + WS_BC0);
  const float* b1c = (const float*)(ws + WS_B1C);
  const float* bo  = (const float*)(ws + WS_BOUT);
  uint32_t* h1p = (uint32_t*)(ws + WS_H1P) + (size_t)g * 8192;
  uint32_t* h2p = (uint32_t*)(ws + WS_H2P) + (size_t)g * 8192;

  __shared__ __align__(16) f16 stage[2][16 * 520];   // staged h panel (padded)

  int budget = SPIN_BUDGET;

  // ---- Resident weight fragments ----
  f16x8 Bh[16];           // Whh0 (L0) or W1c (L1), 16 cols/wave
  f16x8 Bx[8];            // Wih0 (L0)
  f16x8 By[16];           // Wout (L0, waves 0..3)
  float bias = 0.f, ybias = 0.f;
  {
    const int col = j * 128 + wave * 16 + row16;
    const f16* wp = (isL0 ? whh0 : w1c) + (size_t)col * NH + kq * 8;
    #pragma unroll
    for (int kk = 0; kk < 16; kk++) Bh[kk] = *(const f16x8*)(wp + kk * 32);
    bias = (isL0 ? bc0 : b1c)[col];
    if (isL0) {
      const f16* qp = wih0 + (size_t)col * NI + kq * 8;
      #pragma unroll
      for (int kk = 0; kk < 8; kk++) Bx[kk] = *(const f16x8*)(qp + kk * 32);
      if (wave < 4) {
        const int oc = j * 64 + wave * 16 + row16;
        const f16* rp = wout + (size_t)oc * NH + kq * 8;
        #pragma unroll
        for (int kk = 0; kk < 16; kk++) By[kk] = *(const f16x8*)(rp + kk * 32);
        ybias = bo[oc];
      }
    }
  }

  if (isL0) {
    // ================= Layer-0 + output head =================
    for (int t = 0; t <= NT; ++t) {
      // Issue first poll iteration BEFORE the x-part so the two latencies overlap.
      uint32_t w[16];
      #pragma unroll
      for (int i = 0; i < 16; i++)
        w[i] = __hip_atomic_load(h2p + tid + i * 512, __ATOMIC_RELAXED, AGENT);

      // x-part (recurrence-independent)
      f32x4 accx = {0.f, 0.f, 0.f, 0.f};
      if (t < NT) {
        const float* xp = x + ((size_t)(g * 16 + row16) * NT + t) * NI + kq * 8;
        #pragma unroll
        for (int kk = 0; kk < 8; kk++) {
          f32x4 lo = *(const f32x4*)(xp + kk * 32);
          f32x4 hi = *(const f32x4*)(xp + kk * 32 + 4);
          f16x8 a;
          a[0] = (f16)lo[0]; a[1] = (f16)lo[1]; a[2] = (f16)lo[2]; a[3] = (f16)lo[3];
          a[4] = (f16)hi[0]; a[5] = (f16)hi[1]; a[6] = (f16)hi[2]; a[7] = (f16)hi[3];
          accx = mfma16(a, Bx[kk], accx);
        }
      }

      // Poll h2_{t-1}: every thread owns 16 coalesced words (col=tid, rows 0..15).
      poll16(h2p, tid, (uint32_t)t, w, &budget);

      // Unpack straight into LDS stage (the poll WAS the data load).
      f16* st = &stage[t & 1][0];
      #pragma unroll
      for (int i = 0; i < 16; i++) {
        union { uint16_t u; f16 h; } cv;
        cv.u = (uint16_t)(w[i] >> 16);
        st[i * 520 + tid] = cv.h;
      }
      __syncthreads();   // the only barrier per iteration

      const f16* ap = st + row16 * 520 + kq * 8;
      if (t < NT) {
        // h-part: two interleaved accumulator chains halve dependent-MFMA latency.
        f32x4 acc2 = {0.f, 0.f, 0.f, 0.f};
        #pragma unroll
        for (int kk = 0; kk < 16; kk += 2) {
          accx = mfma16(*(const f16x8*)(ap + kk * 32), Bh[kk], accx);
          acc2 = mfma16(*(const f16x8*)(ap + (kk + 1) * 32), Bh[kk + 1], acc2);
        }
        // Publish h1_t directly from registers, tagged t+1. No drain, no flag.
        const int col = j * 128 + wave * 16 + row16;
        const uint32_t tag = (uint32_t)(t + 1);
        #pragma unroll
        for (int rr = 0; rr < 4; rr++) {
          uint32_t wv = pack_h(fast_tanh(accx[rr] + acc2[rr] + bias), tag);
          __hip_atomic_store(h1p + (kq * 4 + rr) * 512 + col, wv,
                             __ATOMIC_RELAXED, AGENT);
        }
      }
      // y_{t-1} = h2_{t-1} Wout^T + bout  (off critical path, after publish)
      if (t > 0 && wave < 4) {
        f32x4 ya = {0.f, 0.f, 0.f, 0.f};
        #pragma unroll
        for (int kk = 0; kk < 16; kk++)
          ya = mfma16(*(const f16x8*)(ap + kk * 32), By[kk], ya);
        const int oc = j * 64 + wave * 16 + row16;
        #pragma unroll
        for (int rr = 0; rr < 4; rr++)
          out[((size_t)(g * 16 + kq * 4 + rr) * NT + (t - 1)) * NO + oc] = ya[rr] + ybias;
      }
    }
  } else {
    // ================= Layer-1 =================
    for (int t = 0; t < NT; ++t) {
      uint32_t w[16];
      #pragma unroll
      for (int i = 0; i < 16; i++)
        w[i] = __hip_atomic_load(h1p + tid + i * 512, __ATOMIC_RELAXED, AGENT);

      poll16(h1p, tid, (uint32_t)(t + 1), w, &budget);

      f16* st = &stage[t & 1][0];
      #pragma unroll
      for (int i = 0; i < 16; i++) {
        union { uint16_t u; f16 h; } cv;
        cv.u = (uint16_t)(w[i] >> 16);
        st[i * 520 + tid] = cv.h;
      }
      __syncthreads();

      const f16* ap = st + row16 * 520 + kq * 8;
      f32x4 a0 = {0.f, 0.f, 0.f, 0.f}, a1 = {0.f, 0.f, 0.f, 0.f};
      #pragma unroll
      for (int kk = 0; kk < 16; kk += 2) {
        a0 = mfma16(*(const f16x8*)(ap + kk * 32), Bh[kk], a0);
        a1 = mfma16(*(const f16x8*)(ap + (kk + 1) * 32), Bh[kk + 1], a1);
      }
      const int col = j * 128 + wave * 16 + row16;
      const uint32_t tag = (uint32_t)(t + 1);
      #pragma unroll
      for (int rr = 0; rr < 4; rr++) {
        uint32_t wv = pack_h(fast_tanh(a0[rr] + a1[rr] + bias), tag);
        __hip_atomic_store(h2p + (kq * 4 + rr) * 512 + col, wv,
                           __ATOMIC_RELAXED, AGENT);
      }
    }
  }
}

extern "C" void kernel_launch(void* const* d_in, const int* in_sizes, int n_in,
                              void* d_out, int out_size, void* d_ws, size_t ws_size,
                              hipStream_t stream) {
  const float* x    = (const float*)d_in[0];
  const float* h0   = (const float*)d_in[1];
  const float* Wih0 = (const float*)d_in[2];
  const float* bih0 = (const float*)d_in[3];
  const float* Whh0 = (const float*)d_in[4];
  const float* bhh0 = (const float*)d_in[5];
  const float* Wih1 = (const float*)d_in[6];
  const float* bih1 = (const float*)d_in[7];
  const float* Whh1 = (const float*)d_in[8];
  const float* bhh1 = (const float*)d_in[9];
  const float* Wout = (const float*)d_in[10];
  const float* bout = (const float*)d_in[11];
  char* ws = (char*)d_ws;
  float* out = (float*)d_out;

  rnn9277_prep<<<dim3(128), dim3(256), 0, stream>>>(
      h0, Wih0, bih0, Whh0, bhh0, Wih1, bih1, Whh1, bhh1, Wout, bout, ws);
  rnn9277_chain<<<dim3(64), dim3(512), 0, stream>>>(x, out, ws);
}